// Round 1
// baseline (2543.419 us; speedup 1.0000x reference)
//
#include <hip/hip_runtime.h>
#include <math.h>

#define BATCH 16
#define NBOX 100000
#define NCLS 30
#define K 200            // PRE_NMS_TOPK
#define MAXDET 100
#define SCORE_THR 0.01f
#define NMS_THR 0.5f

// ---------------------------------------------------------------------------
// Kernel A: per-(b,c) stable top-200 via 4-pass radix select on float bits.
// Stability rule (matches jax.lax.top_k): value desc, index asc.
// ---------------------------------------------------------------------------
__global__ __launch_bounds__(1024) void topk_kernel(const float* __restrict__ cls,
                                                    float* __restrict__ ws_s,
                                                    int* __restrict__ ws_i) {
  const int bc = blockIdx.x;            // 0..479
  const int b = bc / NCLS, c = bc % NCLS;
  const int tid = threadIdx.x;
  const int nth = blockDim.x;           // 1024
  const int wv = tid >> 6;              // wave id 0..15

  __shared__ unsigned hist[16][256];
  __shared__ unsigned long long comb[256];
  __shared__ unsigned eqbuf[512];
  __shared__ unsigned s_pref, s_mask, s_krem, s_takeall;
  __shared__ unsigned s_cntgt, s_cnteq;

  if (tid == 0) { s_pref = 0u; s_mask = 0u; s_krem = K; s_takeall = 0u; }
  __syncthreads();

  const float* col = cls + (size_t)b * NBOX * NCLS + c;

  for (int pass = 0; pass < 4; ++pass) {
    if (s_takeall) break;               // uniform (written before a barrier)
    const int shift = 24 - 8 * pass;
    for (int i = tid; i < 16 * 256; i += nth) ((unsigned*)hist)[i] = 0u;
    __syncthreads();
    const unsigned pref = s_pref, mask = s_mask;
    for (int n = tid; n < NBOX; n += nth) {
      float v = col[(size_t)n * NCLS];
      if (v > SCORE_THR) {
        unsigned key = __float_as_uint(v);    // positive floats: bit order == value order
        if ((key & mask) == pref)
          atomicAdd(&hist[wv][(key >> shift) & 0xFFu], 1u);
      }
    }
    __syncthreads();
    if (tid < 256) {
      unsigned tot = 0;
      for (int w = 0; w < 16; ++w) tot += hist[w][tid];
      hist[0][tid] = tot;
    }
    __syncthreads();
    if (tid == 0) {
      unsigned krem = s_krem, cum = 0; int dsel = -1;
      for (int d = 255; d >= 0; --d) {
        unsigned cnt = hist[0][d];
        if (cum + cnt >= krem) { dsel = d; break; }
        cum += cnt;
      }
      if (dsel < 0) {
        s_takeall = 1u;                 // fewer than K candidates in total
      } else {
        s_krem = krem - cum;
        s_pref = pref | ((unsigned)dsel << shift);
        s_mask = mask | (0xFFu << shift);
      }
    }
    __syncthreads();
  }

  if (tid == 0) { s_cntgt = 0u; s_cnteq = 0u; }
  __syncthreads();
  const unsigned pivot = s_pref;
  const unsigned takeall = s_takeall;

  // Collect pass: strictly-greater -> comb, equal-to-pivot -> eqbuf
  for (int n = tid; n < NBOX; n += nth) {
    float v = col[(size_t)n * NCLS];
    if (v > SCORE_THR) {
      unsigned key = __float_as_uint(v);
      if (takeall || key > pivot) {
        unsigned pos = atomicAdd(&s_cntgt, 1u);
        if (pos < 256u)
          comb[pos] = ((unsigned long long)key << 32) | (unsigned)(~(unsigned)n);
      } else if (key == pivot) {
        unsigned pos = atomicAdd(&s_cnteq, 1u);
        if (pos < 512u) eqbuf[pos] = (unsigned)n;
      }
    }
  }
  __syncthreads();
  const unsigned cntgt = (s_cntgt < 256u) ? s_cntgt : 256u;
  const unsigned cnteq = (s_cnteq < 512u) ? s_cnteq : 512u;
  unsigned need = 0;
  if (!takeall) {
    need = (cntgt < (unsigned)K) ? ((unsigned)K - cntgt) : 0u;
    if (need > cnteq) need = cnteq;
  }
  // pad + ascending bitonic sort of eq indices (smallest indices first)
  for (int i = tid; i < 512; i += nth)
    if ((unsigned)i >= cnteq) eqbuf[i] = 0xFFFFFFFFu;
  for (int k = 2; k <= 512; k <<= 1) {
    for (int j = k >> 1; j > 0; j >>= 1) {
      __syncthreads();
      if (tid < 512) {
        int i = tid, l = i ^ j;
        if (l > i) {
          unsigned a = eqbuf[i], bb = eqbuf[l];
          bool up = ((i & k) == 0);
          if (up ? (a > bb) : (a < bb)) { eqbuf[i] = bb; eqbuf[l] = a; }
        }
      }
    }
  }
  __syncthreads();
  // append pivot-equal candidates; pad rest; descending sort of composites
  for (int t = tid; t < (int)need; t += nth)
    comb[cntgt + t] = ((unsigned long long)pivot << 32) | (unsigned)(~eqbuf[t]);
  const unsigned M = cntgt + need;      // <= 200
  for (int i = tid; i < 256; i += nth)
    if ((unsigned)i >= M) comb[i] = 0ull;
  for (int k = 2; k <= 256; k <<= 1) {
    for (int j = k >> 1; j > 0; j >>= 1) {
      __syncthreads();
      if (tid < 256) {
        int i = tid, l = i ^ j;
        if (l > i) {
          unsigned long long a = comb[i], bb = comb[l];
          bool up = ((i & k) == 0);
          if (up ? (a < bb) : (a > bb)) { comb[i] = bb; comb[l] = a; }  // descending
        }
      }
    }
  }
  __syncthreads();
  if (tid < K) {
    if ((unsigned)tid < M) {
      unsigned long long e = comb[tid];
      ws_s[bc * K + tid] = __uint_as_float((unsigned)(e >> 32));
      ws_i[bc * K + tid] = (int)(~(unsigned)e);
    } else {
      ws_s[bc * K + tid] = -INFINITY;
      ws_i[bc * K + tid] = 0;
    }
  }
}

// ---------------------------------------------------------------------------
// Kernel B: greedy NMS over 200 candidates per (b,c). Exact reference math.
// ---------------------------------------------------------------------------
__global__ __launch_bounds__(256) void nms_kernel(const float* __restrict__ boxes,
                                                  float* __restrict__ ws_s,
                                                  const int* __restrict__ ws_i) {
  const int bc = blockIdx.x;
  const int b = bc / NCLS;
  const int tid = threadIdx.x;
  __shared__ float sx1[K], sy1[K], sx2[K], sy2[K], sarea[K], ss[K];
  __shared__ int skeep[K];

  for (int r = tid; r < K; r += 256) {
    float s = ws_s[bc * K + r];
    int keep = (s != -INFINITY) ? 1 : 0;
    ss[r] = s; skeep[r] = keep;
    float x1 = 0.f, y1 = 0.f, x2 = 0.f, y2 = 0.f;
    if (keep) {
      int idx = ws_i[bc * K + r];
      const float* bp = boxes + ((size_t)b * NBOX + idx) * 4;
      x1 = bp[0]; y1 = bp[1]; x2 = bp[2]; y2 = bp[3];
    }
    sx1[r] = x1; sy1[r] = y1; sx2[r] = x2; sy2[r] = y2;
    sarea[r] = fmaxf(x2 - x1, 0.f) * fmaxf(y2 - y1, 0.f);
  }
  for (int i = 0; i < K; ++i) {
    __syncthreads();
    if (skeep[i]) {
      float xi1 = sx1[i], yi1 = sy1[i], xi2 = sx2[i], yi2 = sy2[i], ai = sarea[i];
      for (int j = i + 1 + tid; j < K; j += 256) {
        if (skeep[j]) {
          float xx1 = fmaxf(xi1, sx1[j]);
          float yy1 = fmaxf(yi1, sy1[j]);
          float xx2 = fminf(xi2, sx2[j]);
          float yy2 = fminf(yi2, sy2[j]);
          float inter = fmaxf(xx2 - xx1, 0.f) * fmaxf(yy2 - yy1, 0.f);
          float uni = ai + sarea[j] - inter;
          float iou = inter / fmaxf(uni, 1e-8f);
          if (iou > NMS_THR) skeep[j] = 0;
        }
      }
    }
  }
  __syncthreads();
  for (int r = tid; r < K; r += 256)
    ws_s[bc * K + r] = skeep[r] ? ss[r] : -INFINITY;
}

// ---------------------------------------------------------------------------
// Kernel C: per-image stable top-100 over 6000 candidates + gather.
// Full bitonic sort of 8192 composite keys in LDS (64KB), then parallel gather.
// ---------------------------------------------------------------------------
__global__ __launch_bounds__(1024) void final_kernel(const float* __restrict__ boxes,
                                                     const float* __restrict__ rot,
                                                     const float* __restrict__ tr,
                                                     const float* __restrict__ ws_s,
                                                     const int* __restrict__ ws_i,
                                                     float* __restrict__ out) {
  const int b = blockIdx.x;
  const int tid = threadIdx.x;
  const int NC = NCLS * K;        // 6000
  const int NS = 8192;
  __shared__ unsigned long long arr[8192];
  const float* sbase = ws_s + (size_t)b * NC;

  for (int f = tid; f < NS; f += 1024) {
    unsigned long long e = 0ull;
    if (f < NC) {
      float s = sbase[f];
      unsigned u = __float_as_uint(s);
      unsigned ord = (u & 0x80000000u) ? ~u : (u | 0x80000000u);  // order-preserving map
      e = ((unsigned long long)ord << 32) | (unsigned)(~(unsigned)f);
    }
    arr[f] = e;
  }
  for (int k = 2; k <= NS; k <<= 1) {
    for (int j = k >> 1; j > 0; j >>= 1) {
      __syncthreads();
      for (int i = tid; i < NS; i += 1024) {
        int l = i ^ j;
        if (l > i) {
          unsigned long long a = arr[i], bb = arr[l];
          bool up = ((i & k) == 0);
          if (up ? (a < bb) : (a > bb)) { arr[i] = bb; arr[l] = a; }  // descending
        }
      }
    }
  }
  __syncthreads();
  if (tid < MAXDET) {
    unsigned long long e = arr[tid];
    unsigned f = ~(unsigned)e;
    float sc = (f < (unsigned)NC) ? sbase[f] : -INFINITY;
    bool valid = (e != 0ull) && (sc != -INFINITY);

    float* ob  = out + ((size_t)b * MAXDET + tid) * 4;
    float* os  = out + (size_t)BATCH * MAXDET * 4 + b * MAXDET + tid;
    float* ol  = os + BATCH * MAXDET;
    float* orr = out + (size_t)BATCH * MAXDET * 6 + ((size_t)b * MAXDET + tid) * 3;
    float* ot  = orr + (size_t)BATCH * MAXDET * 3;

    if (valid) {
      int cl = (int)(f / K);
      int orig = ws_i[(size_t)b * NC + f];
      const float* bp = boxes + ((size_t)b * NBOX + orig) * 4;
      ob[0] = bp[0]; ob[1] = bp[1]; ob[2] = bp[2]; ob[3] = bp[3];
      *os = sc;
      *ol = (float)cl;
      const float* rp = rot + ((size_t)b * NBOX + orig) * 3;
      orr[0] = rp[0]; orr[1] = rp[1]; orr[2] = rp[2];
      const float* tp = tr + ((size_t)b * NBOX + orig) * 3;
      ot[0] = tp[0]; ot[1] = tp[1]; ot[2] = tp[2];
    } else {
      ob[0] = ob[1] = ob[2] = ob[3] = -1.f;
      *os = -1.f; *ol = -1.f;
      orr[0] = orr[1] = orr[2] = -1.f;
      ot[0] = ot[1] = ot[2] = -1.f;
    }
  }
}

extern "C" void kernel_launch(void* const* d_in, const int* in_sizes, int n_in,
                              void* d_out, int out_size, void* d_ws, size_t ws_size,
                              hipStream_t stream) {
  const float* boxes = (const float*)d_in[0];
  const float* cls   = (const float*)d_in[1];
  const float* rot   = (const float*)d_in[2];
  const float* tr    = (const float*)d_in[3];
  float* out = (float*)d_out;

  float* ws_s = (float*)d_ws;                                         // 480*200 floats
  int*   ws_i = (int*)((char*)d_ws + (size_t)BATCH * NCLS * K * 4);   // 480*200 ints

  topk_kernel<<<BATCH * NCLS, 1024, 0, stream>>>(cls, ws_s, ws_i);
  nms_kernel<<<BATCH * NCLS, 256, 0, stream>>>(boxes, ws_s, ws_i);
  final_kernel<<<BATCH, 1024, 0, stream>>>(boxes, rot, tr, ws_s, ws_i, out);
}

// Round 2
// 357.155 us; speedup vs baseline: 7.1213x; 7.1213x over previous
//
#include <hip/hip_runtime.h>
#include <math.h>

#define BATCH 16
#define NBOX 100000
#define NCLS 30
#define K 200            // PRE_NMS_TOPK
#define MAXDET 100
#define SCORE_THR 0.01f
#define NMS_THR 0.5f

#define NBIN 512
#define CHUNKS 16        // chunks per batch
#define ELEM_PER_BATCH (NBOX * NCLS)          // 3,000,000
#define ELEM_PER_CHUNK (ELEM_PER_BATCH / CHUNKS)  // 187,500 (div by 4)
#define CAP 1024

// workspace layout (bytes)
#define OFF_COLL   0ull                                   // u64[480*CAP]    = 3,932,160
#define OFF_HIST   (OFF_COLL + (size_t)BATCH*NCLS*CAP*8)  // u16[16][16][30][512] = 7,864,320
#define OFF_PIVOT  (OFF_HIST + (size_t)BATCH*CHUNKS*NCLS*NBIN*2)  // int[480]
#define OFF_CNT    (OFF_PIVOT + 480*4)
#define OFF_FLAG   (OFF_CNT + 480*4)
#define OFF_WSS    (OFF_FLAG + 480*4)                     // float[480*200]
#define OFF_WSI    (OFF_WSS + (size_t)BATCH*NCLS*K*4)     // int[480*200]

// ---------------------------------------------------------------------------
// 1) Coalesced histogram: 256 blocks (16 batches x 16 chunks), float4 stream.
// ---------------------------------------------------------------------------
__global__ __launch_bounds__(1024) void hist_kernel(const float* __restrict__ cls,
                                                    unsigned short* __restrict__ hist) {
  const int b = blockIdx.x / CHUNKS;
  const int chunk = blockIdx.x % CHUNKS;
  const int tid = threadIdx.x;
  __shared__ unsigned h[NCLS * NBIN];   // 61440 B
  for (int i = tid; i < NCLS * NBIN; i += 1024) h[i] = 0u;
  __syncthreads();

  const size_t base = (size_t)b * ELEM_PER_BATCH + (size_t)chunk * ELEM_PER_CHUNK;
  const float4* p = (const float4*)(cls + base);
  const int nvec = ELEM_PER_CHUNK / 4;   // 46875
  for (int i = tid; i < nvec; i += 1024) {
    float4 v = p[i];
    int e = chunk * ELEM_PER_CHUNK + i * 4;   // element within batch
    float vv[4] = {v.x, v.y, v.z, v.w};
    #pragma unroll
    for (int j = 0; j < 4; ++j) {
      float f = vv[j];
      if (f > SCORE_THR) {
        int bin = (int)(f * (float)NBIN);
        if (bin > NBIN - 1) bin = NBIN - 1;
        int c = (e + j) % NCLS;
        atomicAdd(&h[c * NBIN + bin], 1u);
      }
    }
  }
  __syncthreads();
  unsigned short* dst = hist + ((size_t)(b * CHUNKS + chunk) * NCLS * NBIN);
  for (int i = tid; i < NCLS * NBIN; i += 1024) dst[i] = (unsigned short)h[i];
}

// ---------------------------------------------------------------------------
// 2) Reduce chunk histograms + find pivot bin for rank K. Also zero cnt/flag.
// ---------------------------------------------------------------------------
__global__ __launch_bounds__(256) void pivot_kernel(const unsigned short* __restrict__ hist,
                                                    int* __restrict__ pivot,
                                                    int* __restrict__ cnt,
                                                    int* __restrict__ flag) {
  const int bc = blockIdx.x;
  const int b = bc / NCLS, c = bc % NCLS;
  const int tid = threadIdx.x;
  __shared__ unsigned tot[NBIN];
  for (int bin = tid; bin < NBIN; bin += 256) {
    unsigned s = 0;
    for (int ch = 0; ch < CHUNKS; ++ch)
      s += hist[((size_t)(b * CHUNKS + ch) * NCLS + c) * NBIN + bin];
    tot[bin] = s;
  }
  __syncthreads();
  if (tid == 0) {
    unsigned cum = 0; int d = 0;
    for (int bin = NBIN - 1; bin >= 0; --bin) {
      unsigned cc = tot[bin];
      if (cum + cc >= (unsigned)K) { d = bin; break; }
      cum += cc;
    }
    // if total < K, d stays 0 -> collect everything above threshold (takeall)
    pivot[bc] = d;
    cnt[bc] = 0;
    flag[bc] = 0;
  }
}

// ---------------------------------------------------------------------------
// 3) Coalesced collect: append all entries with bin >= pivot for their class.
// ---------------------------------------------------------------------------
__global__ __launch_bounds__(1024) void collect_kernel(const float* __restrict__ cls,
                                                       const int* __restrict__ pivot,
                                                       int* __restrict__ cnt,
                                                       int* __restrict__ flag,
                                                       unsigned long long* __restrict__ coll) {
  const int b = blockIdx.x / CHUNKS;
  const int chunk = blockIdx.x % CHUNKS;
  const int tid = threadIdx.x;
  __shared__ int piv[NCLS];
  if (tid < NCLS) piv[tid] = pivot[b * NCLS + tid];
  __syncthreads();

  const size_t base = (size_t)b * ELEM_PER_BATCH + (size_t)chunk * ELEM_PER_CHUNK;
  const float4* p = (const float4*)(cls + base);
  const int nvec = ELEM_PER_CHUNK / 4;
  for (int i = tid; i < nvec; i += 1024) {
    float4 v = p[i];
    int e = chunk * ELEM_PER_CHUNK + i * 4;
    float vv[4] = {v.x, v.y, v.z, v.w};
    #pragma unroll
    for (int j = 0; j < 4; ++j) {
      float f = vv[j];
      if (f > SCORE_THR) {
        int bin = (int)(f * (float)NBIN);
        if (bin > NBIN - 1) bin = NBIN - 1;
        int ej = e + j;
        int c = ej % NCLS;
        if (bin >= piv[c]) {
          int n = ej / NCLS;     // box index
          int bc = b * NCLS + c;
          int pos = atomicAdd(&cnt[bc], 1);
          if (pos < CAP) {
            coll[(size_t)bc * CAP + pos] =
              ((unsigned long long)__float_as_uint(f) << 32) | (unsigned)(~(unsigned)n);
          } else {
            flag[bc] = 1;
          }
        }
      }
    }
  }
}

// ---------------------------------------------------------------------------
// 4) Per-(b,c): bitonic-sort collected (<=1024) composites desc, emit top-200.
// ---------------------------------------------------------------------------
__global__ __launch_bounds__(512) void sort_select_kernel(const unsigned long long* __restrict__ coll,
                                                          const int* __restrict__ cnt,
                                                          const int* __restrict__ flag,
                                                          float* __restrict__ ws_s,
                                                          int* __restrict__ ws_i) {
  const int bc = blockIdx.x;
  if (flag[bc]) return;    // fallback kernel handles this (b,c)
  const int tid = threadIdx.x;
  __shared__ unsigned long long arr[CAP];
  const int m = min(cnt[bc], CAP);
  for (int i = tid; i < CAP; i += 512)
    arr[i] = (i < m) ? coll[(size_t)bc * CAP + i] : 0ull;
  for (int k = 2; k <= CAP; k <<= 1) {
    for (int j = k >> 1; j > 0; j >>= 1) {
      __syncthreads();
      for (int i = tid; i < CAP; i += 512) {
        int l = i ^ j;
        if (l > i) {
          unsigned long long a = arr[i], bb = arr[l];
          bool up = ((i & k) == 0);
          if (up ? (a < bb) : (a > bb)) { arr[i] = bb; arr[l] = a; }  // descending
        }
      }
    }
  }
  __syncthreads();
  if (tid < K) {
    unsigned long long e = arr[tid];
    if (e != 0ull) {
      ws_s[bc * K + tid] = __uint_as_float((unsigned)(e >> 32));
      ws_i[bc * K + tid] = (int)(~(unsigned)e);
    } else {
      ws_s[bc * K + tid] = -INFINITY;
      ws_i[bc * K + tid] = 0;
    }
  }
}

// ---------------------------------------------------------------------------
// 4b) Exact radix-select fallback for overflowed (b,c) (adversarial ties).
//     Never triggers on this input; blocks exit immediately.
// ---------------------------------------------------------------------------
__global__ __launch_bounds__(1024) void fallback_kernel(const float* __restrict__ cls,
                                                        const int* __restrict__ flag,
                                                        float* __restrict__ ws_s,
                                                        int* __restrict__ ws_i) {
  const int bc = blockIdx.x;
  if (!flag[bc]) return;
  const int b = bc / NCLS, c = bc % NCLS;
  const int tid = threadIdx.x;
  const int nth = blockDim.x;
  const int wv = tid >> 6;

  __shared__ unsigned hist[16][256];
  __shared__ unsigned long long comb[256];
  __shared__ unsigned eqbuf[512];
  __shared__ unsigned s_pref, s_mask, s_krem, s_takeall;
  __shared__ unsigned s_cntgt, s_cnteq;

  if (tid == 0) { s_pref = 0u; s_mask = 0u; s_krem = K; s_takeall = 0u; }
  __syncthreads();
  const float* col = cls + (size_t)b * NBOX * NCLS + c;

  for (int pass = 0; pass < 4; ++pass) {
    if (s_takeall) break;
    const int shift = 24 - 8 * pass;
    for (int i = tid; i < 16 * 256; i += nth) ((unsigned*)hist)[i] = 0u;
    __syncthreads();
    const unsigned pref = s_pref, mask = s_mask;
    for (int n = tid; n < NBOX; n += nth) {
      float v = col[(size_t)n * NCLS];
      if (v > SCORE_THR) {
        unsigned key = __float_as_uint(v);
        if ((key & mask) == pref)
          atomicAdd(&hist[wv][(key >> shift) & 0xFFu], 1u);
      }
    }
    __syncthreads();
    if (tid < 256) {
      unsigned t2 = 0;
      for (int w = 0; w < 16; ++w) t2 += hist[w][tid];
      hist[0][tid] = t2;
    }
    __syncthreads();
    if (tid == 0) {
      unsigned krem = s_krem, cum = 0; int dsel = -1;
      for (int d = 255; d >= 0; --d) {
        unsigned cc = hist[0][d];
        if (cum + cc >= krem) { dsel = d; break; }
        cum += cc;
      }
      if (dsel < 0) s_takeall = 1u;
      else {
        s_krem = krem - cum;
        s_pref = pref | ((unsigned)dsel << shift);
        s_mask = mask | (0xFFu << shift);
      }
    }
    __syncthreads();
  }

  if (tid == 0) { s_cntgt = 0u; s_cnteq = 0u; }
  __syncthreads();
  const unsigned pivot = s_pref;
  const unsigned takeall = s_takeall;

  for (int n = tid; n < NBOX; n += nth) {
    float v = col[(size_t)n * NCLS];
    if (v > SCORE_THR) {
      unsigned key = __float_as_uint(v);
      if (takeall || key > pivot) {
        unsigned pos = atomicAdd(&s_cntgt, 1u);
        if (pos < 256u)
          comb[pos] = ((unsigned long long)key << 32) | (unsigned)(~(unsigned)n);
      } else if (key == pivot) {
        unsigned pos = atomicAdd(&s_cnteq, 1u);
        if (pos < 512u) eqbuf[pos] = (unsigned)n;
      }
    }
  }
  __syncthreads();
  const unsigned cntgt = (s_cntgt < 256u) ? s_cntgt : 256u;
  const unsigned cnteq = (s_cnteq < 512u) ? s_cnteq : 512u;
  unsigned need = 0;
  if (!takeall) {
    need = (cntgt < (unsigned)K) ? ((unsigned)K - cntgt) : 0u;
    if (need > cnteq) need = cnteq;
  }
  for (int i = tid; i < 512; i += nth)
    if ((unsigned)i >= cnteq) eqbuf[i] = 0xFFFFFFFFu;
  for (int k = 2; k <= 512; k <<= 1) {
    for (int j = k >> 1; j > 0; j >>= 1) {
      __syncthreads();
      if (tid < 512) {
        int i = tid, l = i ^ j;
        if (l > i) {
          unsigned a = eqbuf[i], bb = eqbuf[l];
          bool up = ((i & k) == 0);
          if (up ? (a > bb) : (a < bb)) { eqbuf[i] = bb; eqbuf[l] = a; }
        }
      }
    }
  }
  __syncthreads();
  for (int t = tid; t < (int)need; t += nth)
    comb[cntgt + t] = ((unsigned long long)pivot << 32) | (unsigned)(~eqbuf[t]);
  const unsigned M = cntgt + need;
  for (int i = tid; i < 256; i += nth)
    if ((unsigned)i >= M) comb[i] = 0ull;
  for (int k = 2; k <= 256; k <<= 1) {
    for (int j = k >> 1; j > 0; j >>= 1) {
      __syncthreads();
      if (tid < 256) {
        int i = tid, l = i ^ j;
        if (l > i) {
          unsigned long long a = comb[i], bb = comb[l];
          bool up = ((i & k) == 0);
          if (up ? (a < bb) : (a > bb)) { comb[i] = bb; comb[l] = a; }
        }
      }
    }
  }
  __syncthreads();
  if (tid < K) {
    if ((unsigned)tid < M) {
      unsigned long long e = comb[tid];
      ws_s[bc * K + tid] = __uint_as_float((unsigned)(e >> 32));
      ws_i[bc * K + tid] = (int)(~(unsigned)e);
    } else {
      ws_s[bc * K + tid] = -INFINITY;
      ws_i[bc * K + tid] = 0;
    }
  }
}

// ---------------------------------------------------------------------------
// 5) Greedy NMS over 200 candidates per (b,c). Exact reference math.
// ---------------------------------------------------------------------------
__global__ __launch_bounds__(256) void nms_kernel(const float* __restrict__ boxes,
                                                  float* __restrict__ ws_s,
                                                  const int* __restrict__ ws_i) {
  const int bc = blockIdx.x;
  const int b = bc / NCLS;
  const int tid = threadIdx.x;
  __shared__ float sx1[K], sy1[K], sx2[K], sy2[K], sarea[K], ss[K];
  __shared__ int skeep[K];

  for (int r = tid; r < K; r += 256) {
    float s = ws_s[bc * K + r];
    int keep = (s != -INFINITY) ? 1 : 0;
    ss[r] = s; skeep[r] = keep;
    float x1 = 0.f, y1 = 0.f, x2 = 0.f, y2 = 0.f;
    if (keep) {
      int idx = ws_i[bc * K + r];
      const float* bp = boxes + ((size_t)b * NBOX + idx) * 4;
      x1 = bp[0]; y1 = bp[1]; x2 = bp[2]; y2 = bp[3];
    }
    sx1[r] = x1; sy1[r] = y1; sx2[r] = x2; sy2[r] = y2;
    sarea[r] = fmaxf(x2 - x1, 0.f) * fmaxf(y2 - y1, 0.f);
  }
  for (int i = 0; i < K; ++i) {
    __syncthreads();
    if (skeep[i]) {
      float xi1 = sx1[i], yi1 = sy1[i], xi2 = sx2[i], yi2 = sy2[i], ai = sarea[i];
      for (int j = i + 1 + tid; j < K; j += 256) {
        if (skeep[j]) {
          float xx1 = fmaxf(xi1, sx1[j]);
          float yy1 = fmaxf(yi1, sy1[j]);
          float xx2 = fminf(xi2, sx2[j]);
          float yy2 = fminf(yi2, sy2[j]);
          float inter = fmaxf(xx2 - xx1, 0.f) * fmaxf(yy2 - yy1, 0.f);
          float uni = ai + sarea[j] - inter;
          float iou = inter / fmaxf(uni, 1e-8f);
          if (iou > NMS_THR) skeep[j] = 0;
        }
      }
    }
  }
  __syncthreads();
  for (int r = tid; r < K; r += 256)
    ws_s[bc * K + r] = skeep[r] ? ss[r] : -INFINITY;
}

// ---------------------------------------------------------------------------
// 6) Per-image stable top-100 over 6000 candidates + gather.
// ---------------------------------------------------------------------------
__global__ __launch_bounds__(1024) void final_kernel(const float* __restrict__ boxes,
                                                     const float* __restrict__ rot,
                                                     const float* __restrict__ tr,
                                                     const float* __restrict__ ws_s,
                                                     const int* __restrict__ ws_i,
                                                     float* __restrict__ out) {
  const int b = blockIdx.x;
  const int tid = threadIdx.x;
  const int NC = NCLS * K;        // 6000
  const int NS = 8192;
  __shared__ unsigned long long arr[8192];
  const float* sbase = ws_s + (size_t)b * NC;

  for (int f = tid; f < NS; f += 1024) {
    unsigned long long e = 0ull;
    if (f < NC) {
      float s = sbase[f];
      unsigned u = __float_as_uint(s);
      unsigned ord = (u & 0x80000000u) ? ~u : (u | 0x80000000u);
      e = ((unsigned long long)ord << 32) | (unsigned)(~(unsigned)f);
    }
    arr[f] = e;
  }
  for (int k = 2; k <= NS; k <<= 1) {
    for (int j = k >> 1; j > 0; j >>= 1) {
      __syncthreads();
      for (int i = tid; i < NS; i += 1024) {
        int l = i ^ j;
        if (l > i) {
          unsigned long long a = arr[i], bb = arr[l];
          bool up = ((i & k) == 0);
          if (up ? (a < bb) : (a > bb)) { arr[i] = bb; arr[l] = a; }
        }
      }
    }
  }
  __syncthreads();
  if (tid < MAXDET) {
    unsigned long long e = arr[tid];
    unsigned f = ~(unsigned)e;
    float sc = (f < (unsigned)NC) ? sbase[f] : -INFINITY;
    bool valid = (e != 0ull) && (sc != -INFINITY);

    float* ob  = out + ((size_t)b * MAXDET + tid) * 4;
    float* os  = out + (size_t)BATCH * MAXDET * 4 + b * MAXDET + tid;
    float* ol  = os + BATCH * MAXDET;
    float* orr = out + (size_t)BATCH * MAXDET * 6 + ((size_t)b * MAXDET + tid) * 3;
    float* ot  = orr + (size_t)BATCH * MAXDET * 3;

    if (valid) {
      int cl = (int)(f / K);
      int orig = ws_i[(size_t)b * NC + f];
      const float* bp = boxes + ((size_t)b * NBOX + orig) * 4;
      ob[0] = bp[0]; ob[1] = bp[1]; ob[2] = bp[2]; ob[3] = bp[3];
      *os = sc;
      *ol = (float)cl;
      const float* rp = rot + ((size_t)b * NBOX + orig) * 3;
      orr[0] = rp[0]; orr[1] = rp[1]; orr[2] = rp[2];
      const float* tp = tr + ((size_t)b * NBOX + orig) * 3;
      ot[0] = tp[0]; ot[1] = tp[1]; ot[2] = tp[2];
    } else {
      ob[0] = ob[1] = ob[2] = ob[3] = -1.f;
      *os = -1.f; *ol = -1.f;
      orr[0] = orr[1] = orr[2] = -1.f;
      ot[0] = ot[1] = ot[2] = -1.f;
    }
  }
}

extern "C" void kernel_launch(void* const* d_in, const int* in_sizes, int n_in,
                              void* d_out, int out_size, void* d_ws, size_t ws_size,
                              hipStream_t stream) {
  const float* boxes = (const float*)d_in[0];
  const float* cls   = (const float*)d_in[1];
  const float* rot   = (const float*)d_in[2];
  const float* tr    = (const float*)d_in[3];
  float* out = (float*)d_out;

  char* ws = (char*)d_ws;
  unsigned long long* coll = (unsigned long long*)(ws + OFF_COLL);
  unsigned short*     hist = (unsigned short*)(ws + OFF_HIST);
  int*   pivot = (int*)(ws + OFF_PIVOT);
  int*   cnt   = (int*)(ws + OFF_CNT);
  int*   flag  = (int*)(ws + OFF_FLAG);
  float* ws_s  = (float*)(ws + OFF_WSS);
  int*   ws_i  = (int*)(ws + OFF_WSI);

  hist_kernel<<<BATCH * CHUNKS, 1024, 0, stream>>>(cls, hist);
  pivot_kernel<<<BATCH * NCLS, 256, 0, stream>>>(hist, pivot, cnt, flag);
  collect_kernel<<<BATCH * CHUNKS, 1024, 0, stream>>>(cls, pivot, cnt, flag, coll);
  sort_select_kernel<<<BATCH * NCLS, 512, 0, stream>>>(coll, cnt, flag, ws_s, ws_i);
  fallback_kernel<<<BATCH * NCLS, 1024, 0, stream>>>(cls, flag, ws_s, ws_i);
  nms_kernel<<<BATCH * NCLS, 256, 0, stream>>>(boxes, ws_s, ws_i);
  final_kernel<<<BATCH, 1024, 0, stream>>>(boxes, rot, tr, ws_s, ws_i, out);
}

// Round 3
// 223.881 us; speedup vs baseline: 11.3606x; 1.5953x over previous
//
#include <hip/hip_runtime.h>
#include <math.h>

typedef unsigned long long u64;

#define BATCH 16
#define NBOX 100000
#define NCLS 30
#define K 200            // PRE_NMS_TOPK
#define MAXDET 100
#define SCORE_THR 0.01f
#define NMS_THR 0.5f

#define NBIN 512
#define CHUNKS 16
#define ELEM_PER_BATCH (NBOX * NCLS)              // 3,000,000
#define ELEM_PER_CHUNK (ELEM_PER_BATCH / CHUNKS)  // 187,500
#define CAP 1024

// workspace layout (bytes)
#define OFF_COLL   0ull                                            // u64[480*CAP]
#define OFF_HIST   (OFF_COLL + (size_t)BATCH*NCLS*CAP*8)           // u16[256][30][512]
#define OFF_PIVOT  (OFF_HIST + (size_t)BATCH*CHUNKS*NCLS*NBIN*2)
#define OFF_CNT    (OFF_PIVOT + 480*4)
#define OFF_FLAG   (OFF_CNT + 480*4)
#define OFF_WSS    (OFF_FLAG + 480*4)                              // float[480*200] (fallback only)
#define OFF_WSI    (OFF_WSS + (size_t)BATCH*NCLS*K*4)              // int[480*200]
#define OFF_MERGE  (OFF_WSI + (size_t)BATCH*NCLS*K*4)              // u64[16][32][128]

// ---------------------------------------------------------------------------
// 1) Coalesced histogram: 256 blocks (16 batches x 16 chunks), float4 stream.
// ---------------------------------------------------------------------------
__global__ __launch_bounds__(1024) void hist_kernel(const float* __restrict__ cls,
                                                    unsigned short* __restrict__ hist) {
  const int b = blockIdx.x / CHUNKS;
  const int chunk = blockIdx.x % CHUNKS;
  const int tid = threadIdx.x;
  __shared__ unsigned h[NCLS * NBIN];
  for (int i = tid; i < NCLS * NBIN; i += 1024) h[i] = 0u;
  __syncthreads();

  const size_t base = (size_t)b * ELEM_PER_BATCH + (size_t)chunk * ELEM_PER_CHUNK;
  const float4* p = (const float4*)(cls + base);
  const int nvec = ELEM_PER_CHUNK / 4;
  for (int i = tid; i < nvec; i += 1024) {
    float4 v = p[i];
    int e = chunk * ELEM_PER_CHUNK + i * 4;
    float vv[4] = {v.x, v.y, v.z, v.w};
    #pragma unroll
    for (int j = 0; j < 4; ++j) {
      float f = vv[j];
      if (f > SCORE_THR) {
        int bin = (int)(f * (float)NBIN);
        if (bin > NBIN - 1) bin = NBIN - 1;
        int c = (e + j) % NCLS;
        atomicAdd(&h[c * NBIN + bin], 1u);
      }
    }
  }
  __syncthreads();
  unsigned short* dst = hist + ((size_t)(b * CHUNKS + chunk) * NCLS * NBIN);
  for (int i = tid; i < NCLS * NBIN; i += 1024) dst[i] = (unsigned short)h[i];
}

// ---------------------------------------------------------------------------
// 2) Reduce chunk histograms + pivot bin for rank K; zero cnt/flag.
// ---------------------------------------------------------------------------
__global__ __launch_bounds__(256) void pivot_kernel(const unsigned short* __restrict__ hist,
                                                    int* __restrict__ pivot,
                                                    int* __restrict__ cnt,
                                                    int* __restrict__ flag) {
  const int bc = blockIdx.x;
  const int b = bc / NCLS, c = bc % NCLS;
  const int tid = threadIdx.x;
  __shared__ unsigned tot[NBIN];
  for (int bin = tid; bin < NBIN; bin += 256) {
    unsigned s = 0;
    for (int ch = 0; ch < CHUNKS; ++ch)
      s += hist[((size_t)(b * CHUNKS + ch) * NCLS + c) * NBIN + bin];
    tot[bin] = s;
  }
  __syncthreads();
  if (tid == 0) {
    unsigned cum = 0; int d = 0;
    for (int bin = NBIN - 1; bin >= 0; --bin) {
      unsigned cc = tot[bin];
      if (cum + cc >= (unsigned)K) { d = bin; break; }
      cum += cc;
    }
    pivot[bc] = d;
    cnt[bc] = 0;
    flag[bc] = 0;
  }
}

// ---------------------------------------------------------------------------
// 3) Coalesced collect: append entries with bin >= pivot for their class.
// ---------------------------------------------------------------------------
__global__ __launch_bounds__(1024) void collect_kernel(const float* __restrict__ cls,
                                                       const int* __restrict__ pivot,
                                                       int* __restrict__ cnt,
                                                       int* __restrict__ flag,
                                                       u64* __restrict__ coll) {
  const int b = blockIdx.x / CHUNKS;
  const int chunk = blockIdx.x % CHUNKS;
  const int tid = threadIdx.x;
  __shared__ int piv[NCLS];
  if (tid < NCLS) piv[tid] = pivot[b * NCLS + tid];
  __syncthreads();

  const size_t base = (size_t)b * ELEM_PER_BATCH + (size_t)chunk * ELEM_PER_CHUNK;
  const float4* p = (const float4*)(cls + base);
  const int nvec = ELEM_PER_CHUNK / 4;
  for (int i = tid; i < nvec; i += 1024) {
    float4 v = p[i];
    int e = chunk * ELEM_PER_CHUNK + i * 4;
    float vv[4] = {v.x, v.y, v.z, v.w};
    #pragma unroll
    for (int j = 0; j < 4; ++j) {
      float f = vv[j];
      if (f > SCORE_THR) {
        int bin = (int)(f * (float)NBIN);
        if (bin > NBIN - 1) bin = NBIN - 1;
        int ej = e + j;
        int c = ej % NCLS;
        if (bin >= piv[c]) {
          int n = ej / NCLS;
          int bc = b * NCLS + c;
          int pos = atomicAdd(&cnt[bc], 1);
          if (pos < CAP) {
            coll[(size_t)bc * CAP + pos] =
              ((u64)__float_as_uint(f) << 32) | (unsigned)(~(unsigned)n);
          } else {
            flag[bc] = 1;
          }
        }
      }
    }
  }
}

// ---------------------------------------------------------------------------
// 3b) Exact radix-select fallback for overflowed (b,c). Normally a no-op.
// ---------------------------------------------------------------------------
__global__ __launch_bounds__(1024) void fallback_kernel(const float* __restrict__ cls,
                                                        const int* __restrict__ flag,
                                                        float* __restrict__ ws_s,
                                                        int* __restrict__ ws_i) {
  const int bc = blockIdx.x;
  if (!flag[bc]) return;
  const int b = bc / NCLS, c = bc % NCLS;
  const int tid = threadIdx.x;
  const int nth = blockDim.x;
  const int wv = tid >> 6;

  __shared__ unsigned hist[16][256];
  __shared__ u64 comb[256];
  __shared__ unsigned eqbuf[512];
  __shared__ unsigned s_pref, s_mask, s_krem, s_takeall;
  __shared__ unsigned s_cntgt, s_cnteq;

  if (tid == 0) { s_pref = 0u; s_mask = 0u; s_krem = K; s_takeall = 0u; }
  __syncthreads();
  const float* col = cls + (size_t)b * NBOX * NCLS + c;

  for (int pass = 0; pass < 4; ++pass) {
    if (s_takeall) break;
    const int shift = 24 - 8 * pass;
    for (int i = tid; i < 16 * 256; i += nth) ((unsigned*)hist)[i] = 0u;
    __syncthreads();
    const unsigned pref = s_pref, mask = s_mask;
    for (int n = tid; n < NBOX; n += nth) {
      float v = col[(size_t)n * NCLS];
      if (v > SCORE_THR) {
        unsigned key = __float_as_uint(v);
        if ((key & mask) == pref)
          atomicAdd(&hist[wv][(key >> shift) & 0xFFu], 1u);
      }
    }
    __syncthreads();
    if (tid < 256) {
      unsigned t2 = 0;
      for (int w = 0; w < 16; ++w) t2 += hist[w][tid];
      hist[0][tid] = t2;
    }
    __syncthreads();
    if (tid == 0) {
      unsigned krem = s_krem, cum = 0; int dsel = -1;
      for (int d = 255; d >= 0; --d) {
        unsigned cc = hist[0][d];
        if (cum + cc >= krem) { dsel = d; break; }
        cum += cc;
      }
      if (dsel < 0) s_takeall = 1u;
      else {
        s_krem = krem - cum;
        s_pref = pref | ((unsigned)dsel << shift);
        s_mask = mask | (0xFFu << shift);
      }
    }
    __syncthreads();
  }

  if (tid == 0) { s_cntgt = 0u; s_cnteq = 0u; }
  __syncthreads();
  const unsigned pivot = s_pref;
  const unsigned takeall = s_takeall;

  for (int n = tid; n < NBOX; n += nth) {
    float v = col[(size_t)n * NCLS];
    if (v > SCORE_THR) {
      unsigned key = __float_as_uint(v);
      if (takeall || key > pivot) {
        unsigned pos = atomicAdd(&s_cntgt, 1u);
        if (pos < 256u)
          comb[pos] = ((u64)key << 32) | (unsigned)(~(unsigned)n);
      } else if (key == pivot) {
        unsigned pos = atomicAdd(&s_cnteq, 1u);
        if (pos < 512u) eqbuf[pos] = (unsigned)n;
      }
    }
  }
  __syncthreads();
  const unsigned cntgt = (s_cntgt < 256u) ? s_cntgt : 256u;
  const unsigned cnteq = (s_cnteq < 512u) ? s_cnteq : 512u;
  unsigned need = 0;
  if (!takeall) {
    need = (cntgt < (unsigned)K) ? ((unsigned)K - cntgt) : 0u;
    if (need > cnteq) need = cnteq;
  }
  for (int i = tid; i < 512; i += nth)
    if ((unsigned)i >= cnteq) eqbuf[i] = 0xFFFFFFFFu;
  for (int k = 2; k <= 512; k <<= 1) {
    for (int j = k >> 1; j > 0; j >>= 1) {
      __syncthreads();
      if (tid < 512) {
        int i = tid, l = i ^ j;
        if (l > i) {
          unsigned a = eqbuf[i], bb = eqbuf[l];
          bool up = ((i & k) == 0);
          if (up ? (a > bb) : (a < bb)) { eqbuf[i] = bb; eqbuf[l] = a; }
        }
      }
    }
  }
  __syncthreads();
  for (int t = tid; t < (int)need; t += nth)
    comb[cntgt + t] = ((u64)pivot << 32) | (unsigned)(~eqbuf[t]);
  const unsigned M = cntgt + need;
  for (int i = tid; i < 256; i += nth)
    if ((unsigned)i >= M) comb[i] = 0ull;
  for (int k = 2; k <= 256; k <<= 1) {
    for (int j = k >> 1; j > 0; j >>= 1) {
      __syncthreads();
      if (tid < 256) {
        int i = tid, l = i ^ j;
        if (l > i) {
          u64 a = comb[i], bb = comb[l];
          bool up = ((i & k) == 0);
          if (up ? (a < bb) : (a > bb)) { comb[i] = bb; comb[l] = a; }
        }
      }
    }
  }
  __syncthreads();
  if (tid < K) {
    if ((unsigned)tid < M) {
      u64 e = comb[tid];
      ws_s[bc * K + tid] = __uint_as_float((unsigned)(e >> 32));
      ws_i[bc * K + tid] = (int)(~(unsigned)e);
    } else {
      ws_s[bc * K + tid] = -INFINITY;
      ws_i[bc * K + tid] = 0;
    }
  }
}

// ---------------------------------------------------------------------------
// 4) Fused: sort candidates -> top-200 -> bitmask NMS -> stable compaction ->
//    emit sorted per-class key list (top-128) for the merge tournament.
// ---------------------------------------------------------------------------
__global__ __launch_bounds__(512) void fused_sort_nms_kernel(
    const u64* __restrict__ coll, const int* __restrict__ cnt,
    const int* __restrict__ flag,
    const float* __restrict__ ws_s_fb, const int* __restrict__ ws_i_fb,
    const float* __restrict__ boxes,
    int* __restrict__ ws_i, u64* __restrict__ merged) {
  const int bc = blockIdx.x;
  const int b = bc / NCLS, c = bc % NCLS;
  const int tid = threadIdx.x;

  __shared__ u64 arr[CAP];
  __shared__ float sx1[K], sy1[K], sx2[K], sy2[K], sarea[K], ss[K];
  __shared__ int sidx[K];
  __shared__ unsigned mask[K][8];
  __shared__ unsigned keepw[8];
  __shared__ int s_surv;

  const int isflag = flag[bc];
  if (!isflag) {
    const int m = min(cnt[bc], CAP);
    for (int i = tid; i < CAP; i += 512)
      arr[i] = (i < m) ? coll[(size_t)bc * CAP + i] : 0ull;
    for (int k = 2; k <= CAP; k <<= 1) {
      for (int j = k >> 1; j > 0; j >>= 1) {
        __syncthreads();
        for (int i = tid; i < CAP; i += 512) {
          int l = i ^ j;
          if (l > i) {
            u64 a = arr[i], bb = arr[l];
            bool up = ((i & k) == 0);
            if (up ? (a < bb) : (a > bb)) { arr[i] = bb; arr[l] = a; }
          }
        }
      }
    }
    __syncthreads();
    for (int r = tid; r < K; r += 512) {
      u64 e = arr[r];
      float s = (e != 0ull) ? __uint_as_float((unsigned)(e >> 32)) : -INFINITY;
      int idx = (e != 0ull) ? (int)(~(unsigned)e) : 0;
      ss[r] = s; sidx[r] = idx;
      ws_i[bc * K + r] = idx;
    }
  } else {
    for (int r = tid; r < K; r += 512) {
      ss[r] = ws_s_fb[bc * K + r];
      sidx[r] = ws_i_fb[bc * K + r];
    }
  }
  for (int i = tid; i < K * 8; i += 512) ((unsigned*)mask)[i] = 0u;
  if (tid < 8) keepw[tid] = 0u;
  __syncthreads();

  for (int r = tid; r < K; r += 512) {
    float s = ss[r];
    bool valid = (s != -INFINITY);
    float x1 = 0.f, y1 = 0.f, x2 = 0.f, y2 = 0.f;
    if (valid) {
      const float* bp = boxes + ((size_t)b * NBOX + sidx[r]) * 4;
      x1 = bp[0]; y1 = bp[1]; x2 = bp[2]; y2 = bp[3];
      atomicOr(&keepw[r >> 5], 1u << (r & 31));
    }
    sx1[r] = x1; sy1[r] = y1; sx2[r] = x2; sy2[r] = y2;
    sarea[r] = fmaxf(x2 - x1, 0.f) * fmaxf(y2 - y1, 0.f);
  }
  __syncthreads();

  // pairwise suppression bitmask, j > i (fully parallel, no barriers)
  for (int t = tid; t < K * K; t += 512) {
    int i = t / K, j = t - i * K;
    if (j > i) {
      float xx1 = fmaxf(sx1[i], sx1[j]);
      float yy1 = fmaxf(sy1[i], sy1[j]);
      float xx2 = fminf(sx2[i], sx2[j]);
      float yy2 = fminf(sy2[i], sy2[j]);
      float inter = fmaxf(xx2 - xx1, 0.f) * fmaxf(yy2 - yy1, 0.f);
      float uni = sarea[i] + sarea[j] - inter;
      float iou = inter / fmaxf(uni, 1e-8f);
      if (iou > NMS_THR) atomicOr(&mask[i][j >> 5], 1u << (j & 31));
    }
  }
  __syncthreads();

  // serial greedy scan on wave 0 (wave-synchronous, no barriers)
  if (tid < 64) {
    int w = tid & 7;
    unsigned keep = keepw[w];
    for (int i = 0; i < K; ++i) {
      unsigned kw = __shfl(keep, i >> 5, 64);
      if ((kw >> (i & 31)) & 1u)
        keep &= ~mask[i][w];
    }
    if (tid < 8) keepw[tid] = keep;
  }
  __syncthreads();

  // stable compaction + key emission (per-class list is sorted desc by key)
  for (int r = tid; r < K; r += 512) {
    int w6 = r >> 5, bit = r & 31;
    if ((keepw[w6] >> bit) & 1u) {
      int pos = 0;
      #pragma unroll
      for (int w = 0; w < 7; ++w) {
        unsigned kw = keepw[w];
        if (w < w6) pos += __popc(kw);
        else if (w == w6) pos += __popc(kw & ((1u << bit) - 1u));
      }
      if (pos < 128) {
        unsigned ord = __float_as_uint(ss[r]) | 0x80000000u;
        merged[((size_t)b * 32 + c) * 128 + pos] =
          ((u64)ord << 32) | (unsigned)(~(unsigned)(c * K + r));
      }
    }
  }
  if (tid == 0) {
    int S = 0;
    #pragma unroll
    for (int w = 0; w < 7; ++w) S += __popc(keepw[w]);
    s_surv = S;
  }
  __syncthreads();
  for (int t = s_surv + tid; t < 128; t += 512)
    merged[((size_t)b * 32 + c) * 128 + t] = 0ull;
}

// ---------------------------------------------------------------------------
// 5) Per-image merge tournament: 32 sorted lists of 128 -> top-128 -> gather.
// ---------------------------------------------------------------------------
__global__ __launch_bounds__(1024) void merge_gather_kernel(
    const u64* __restrict__ merged, const int* __restrict__ ws_i,
    const float* __restrict__ boxes, const float* __restrict__ rot,
    const float* __restrict__ tr, float* __restrict__ out) {
  const int b = blockIdx.x;
  const int tid = threadIdx.x;
  __shared__ u64 W[4096];

  for (int t = tid; t < 4096; t += 1024) {
    int c = t >> 7, r = t & 127;
    W[t] = (c < NCLS) ? merged[((size_t)b * 32 + c) * 128 + r] : 0ull;
  }
  __syncthreads();

  int active = 4096;
  #pragma unroll
  for (int level = 0; level < 5; ++level) {
    int npairs = active >> 8;
    // reverse odd half of each 256 region -> bitonic
    for (int t = tid; t < npairs * 64; t += 1024) {
      int p = t >> 6, q = t & 63;
      int i1 = p * 256 + 128 + q, i2 = p * 256 + 255 - q;
      u64 a = W[i1]; W[i1] = W[i2]; W[i2] = a;
    }
    __syncthreads();
    // bitonic merge, descending
    for (int j = 128; j > 0; j >>= 1) {
      for (int i = tid; i < active; i += 1024) {
        int l = i ^ j;
        if (l > i) {
          u64 a = W[i], bb = W[l];
          if (a < bb) { W[i] = bb; W[l] = a; }
        }
      }
      __syncthreads();
    }
    // keep top-128 of each region, compact to front
    int half = active >> 1;
    u64 t0 = 0, t1 = 0;
    if (tid < half) t0 = W[(tid >> 7) * 256 + (tid & 127)];
    int t2i = tid + 1024;
    if (t2i < half) t1 = W[(t2i >> 7) * 256 + (t2i & 127)];
    __syncthreads();
    if (tid < half) W[tid] = t0;
    if (t2i < half) W[t2i] = t1;
    __syncthreads();
    active = half;
  }

  if (tid < MAXDET) {
    u64 key = W[tid];
    bool valid = (key != 0ull);
    float* ob  = out + ((size_t)b * MAXDET + tid) * 4;
    float* os  = out + (size_t)BATCH * MAXDET * 4 + b * MAXDET + tid;
    float* ol  = os + BATCH * MAXDET;
    float* orr = out + (size_t)BATCH * MAXDET * 6 + ((size_t)b * MAXDET + tid) * 3;
    float* ot  = orr + (size_t)BATCH * MAXDET * 3;

    if (valid) {
      unsigned f = ~(unsigned)key;            // flat = c*K + r
      int cl = (int)(f / K);
      float sc = __uint_as_float((unsigned)(key >> 32) & 0x7FFFFFFFu);
      int orig = ws_i[(size_t)b * NCLS * K + f];
      const float* bp = boxes + ((size_t)b * NBOX + orig) * 4;
      ob[0] = bp[0]; ob[1] = bp[1]; ob[2] = bp[2]; ob[3] = bp[3];
      *os = sc;
      *ol = (float)cl;
      const float* rp = rot + ((size_t)b * NBOX + orig) * 3;
      orr[0] = rp[0]; orr[1] = rp[1]; orr[2] = rp[2];
      const float* tp = tr + ((size_t)b * NBOX + orig) * 3;
      ot[0] = tp[0]; ot[1] = tp[1]; ot[2] = tp[2];
    } else {
      ob[0] = ob[1] = ob[2] = ob[3] = -1.f;
      *os = -1.f; *ol = -1.f;
      orr[0] = orr[1] = orr[2] = -1.f;
      ot[0] = ot[1] = ot[2] = -1.f;
    }
  }
}

extern "C" void kernel_launch(void* const* d_in, const int* in_sizes, int n_in,
                              void* d_out, int out_size, void* d_ws, size_t ws_size,
                              hipStream_t stream) {
  const float* boxes = (const float*)d_in[0];
  const float* cls   = (const float*)d_in[1];
  const float* rot   = (const float*)d_in[2];
  const float* tr    = (const float*)d_in[3];
  float* out = (float*)d_out;

  char* ws = (char*)d_ws;
  u64*            coll   = (u64*)(ws + OFF_COLL);
  unsigned short* hist   = (unsigned short*)(ws + OFF_HIST);
  int*   pivot  = (int*)(ws + OFF_PIVOT);
  int*   cnt    = (int*)(ws + OFF_CNT);
  int*   flag   = (int*)(ws + OFF_FLAG);
  float* ws_s   = (float*)(ws + OFF_WSS);
  int*   ws_i   = (int*)(ws + OFF_WSI);
  u64*   merged = (u64*)(ws + OFF_MERGE);

  hist_kernel<<<BATCH * CHUNKS, 1024, 0, stream>>>(cls, hist);
  pivot_kernel<<<BATCH * NCLS, 256, 0, stream>>>(hist, pivot, cnt, flag);
  collect_kernel<<<BATCH * CHUNKS, 1024, 0, stream>>>(cls, pivot, cnt, flag, coll);
  fallback_kernel<<<BATCH * NCLS, 1024, 0, stream>>>(cls, flag, ws_s, ws_i);
  fused_sort_nms_kernel<<<BATCH * NCLS, 512, 0, stream>>>(coll, cnt, flag, ws_s, ws_i,
                                                          boxes, ws_i, merged);
  merge_gather_kernel<<<BATCH, 1024, 0, stream>>>(merged, ws_i, boxes, rot, tr, out);
}